// Round 14
// baseline (197.287 us; speedup 1.0000x reference)
//
#include <hip/hip_runtime.h>

// GraphSAGE 2-layer (mean agg), N=100K, E=1.6M, 128->128->64, f32 in/out.
// PERSISTENT fused GEMM v2: swapped MFMA operands (A=W,B=X) so C's lane&15 =
// node -> vectorized epilogues (b64 LDS writes for h1, u32/float4 global for
// p8/s2). W2 held in registers (no W2s LDS, no GEMM2 B reads). BM=128,
// 8 waves (2node x 4j), wave tile 64node x 32j. LDS = W1s 64KB + Xs 64KB.
// Full 16-lane granule swizzle (^ idx&15) -> conflict-free b128 reads.
// Degree-sort REMOVED (R13 post-mortem: net -6us). CSR via bucketed sort.
// Overlays: p8->bed (dead after CSR), s2f->aggb (tile-local rows, WAR-safe).

typedef __attribute__((ext_vector_type(8))) short short8;
typedef __attribute__((ext_vector_type(4))) float f32x4;
typedef __attribute__((ext_vector_type(2))) float f32x2;

__device__ __forceinline__ ushort f2bf(float f) {
  uint u = __float_as_uint(f);
  u += 0x7fffu + ((u >> 16) & 1u);  // round-to-nearest-even
  return (ushort)(u >> 16);
}

#define GLDS(src, dst)                                                        \
  __builtin_amdgcn_global_load_lds(                                           \
      (const __attribute__((address_space(1))) void*)(src),                   \
      (__attribute__((address_space(3))) void*)(dst), 16, 0, 0)

#define FENCE() asm volatile("" ::: "memory")
#define LGKM0() asm volatile("s_waitcnt lgkmcnt(0)" ::: "memory")

// ================= bucketed CSR build =================
__global__ __launch_bounds__(256) void k_bhist(const int* __restrict__ dst,
                                               int* __restrict__ bcnt, int E) {
  __shared__ int h[512];
  int t = threadIdx.x;
  for (int i = t; i < 512; i += 256) h[i] = 0;
  __syncthreads();
  int base = blockIdx.x * 8192;
  int end = min(base + 8192, E);
  for (int e = base + t; e < end; e += 256)
    atomicAdd(&h[((uint)dst[e]) >> 8], 1);
  __syncthreads();
  for (int i = t; i < 512; i += 256)
    if (h[i]) atomicAdd(&bcnt[i], h[i]);
}

__global__ __launch_bounds__(512) void k_bscan(const int* __restrict__ bcnt,
                                               int* __restrict__ bbase,
                                               int* __restrict__ bcur, int P, int E) {
  __shared__ int s[512];
  int t = threadIdx.x;
  int v = (t < P) ? bcnt[t] : 0;
  s[t] = v;
  __syncthreads();
  for (int off = 1; off < 512; off <<= 1) {
    int x = (t >= off) ? s[t - off] : 0;
    __syncthreads();
    s[t] += x;
    __syncthreads();
  }
  int ex = s[t] - v;
  if (t < P) {
    bbase[t] = ex;
    bcur[t] = ex;
  }
  if (t == P - 1) bbase[P] = E;
}

__global__ __launch_bounds__(256) void k_bscatter(const int* __restrict__ dst,
                                                  const int* __restrict__ src,
                                                  int* __restrict__ bcur,
                                                  uint* __restrict__ bed, int E, int P) {
  __shared__ int hist[512];
  __shared__ int incl[512];
  __shared__ int gpos[512];
  __shared__ int cur[512];
  __shared__ uint stage[8192];
  __shared__ ushort bof[8192];
  int t = threadIdx.x;
  int base = blockIdx.x * 8192;
  int cnt = min(8192, E - base);
  for (int i = t; i < 512; i += 256) hist[i] = 0;
  __syncthreads();
  for (int i = t; i < cnt; i += 256)
    atomicAdd(&hist[((uint)dst[base + i]) >> 8], 1);
  __syncthreads();
  incl[t] = hist[t];
  incl[t + 256] = hist[t + 256];
  __syncthreads();
  for (int off = 1; off < 512; off <<= 1) {
    int i0 = t, i1 = t + 256;
    int a0 = (i0 >= off) ? incl[i0 - off] : 0;
    int a1 = (i1 >= off) ? incl[i1 - off] : 0;
    __syncthreads();
    incl[i0] += a0;
    incl[i1] += a1;
    __syncthreads();
  }
  cur[t] = incl[t] - hist[t];
  cur[t + 256] = incl[t + 256] - hist[t + 256];
  for (int i = t; i < P; i += 256)
    if (hist[i]) gpos[i] = atomicAdd(&bcur[i], hist[i]);
  __syncthreads();
  for (int i = t; i < cnt; i += 256) {
    int d = dst[base + i];
    int b = ((uint)d) >> 8;
    uint val = (((uint)src[base + i]) << 8) | (uint)(d & 255);
    int slot = atomicAdd(&cur[b], 1);
    stage[slot] = val;
    bof[slot] = (ushort)b;
  }
  __syncthreads();
  for (int i = t; i < cnt; i += 256) {
    int b = bof[i];
    int ex = incl[b] - hist[b];
    bed[gpos[b] + (i - ex)] = stage[i];
  }
}

__global__ __launch_bounds__(256) void k_bcsr(const uint* __restrict__ bed,
                                              const int* __restrict__ bbase,
                                              int* __restrict__ deg,
                                              int* __restrict__ rs,
                                              int* __restrict__ col, int N) {
  __shared__ int dcnt[256];
  __shared__ int sofs[256];
  int b = blockIdx.x, t = threadIdx.x;
  int e0 = bbase[b], e1 = bbase[b + 1];
  dcnt[t] = 0;
  __syncthreads();
  for (int e = e0 + t; e < e1; e += 256) atomicAdd(&dcnt[bed[e] & 255u], 1);
  __syncthreads();
  int v0 = dcnt[t];
  sofs[t] = v0;
  __syncthreads();
  for (int off = 1; off < 256; off <<= 1) {
    int x = (t >= off) ? sofs[t - off] : 0;
    __syncthreads();
    sofs[t] += x;
    __syncthreads();
  }
  int ex = sofs[t] - v0;
  int node = (b << 8) + t;
  if (node < N) {
    deg[node] = v0;
    rs[node] = e0 + ex;
  }
  __syncthreads();
  dcnt[t] = e0 + ex;
  __syncthreads();
  for (int e = e0 + t; e < e1; e += 256) {
    uint v = bed[e];
    int pos = atomicAdd(&dcnt[v & 255u], 1);
    col[pos] = (int)(v >> 8);
  }
}

// -------- prep: f32 h -> bf16 hb (GEMM) + fp8 h8 (gather) --------
__global__ __launch_bounds__(256) void k_cast(const float* __restrict__ in,
                                              ushort* __restrict__ outb,
                                              uchar* __restrict__ out8, int n8) {
  int i = blockIdx.x * 256 + threadIdx.x;
  if (i >= n8) return;
  const float4* p = reinterpret_cast<const float4*>(in) + i * 2;
  float4 a = p[0], b = p[1];
  ushort u[8];
  u[0] = f2bf(a.x); u[1] = f2bf(a.y); u[2] = f2bf(a.z); u[3] = f2bf(a.w);
  u[4] = f2bf(b.x); u[5] = f2bf(b.y); u[6] = f2bf(b.z); u[7] = f2bf(b.w);
  *reinterpret_cast<ulonglong2*>(outb + (size_t)i * 8) =
      *reinterpret_cast<ulonglong2*>(u);
  uint2 q;
  int w0 = __builtin_amdgcn_cvt_pk_fp8_f32(a.x, a.y, 0, false);
  w0 = __builtin_amdgcn_cvt_pk_fp8_f32(a.z, a.w, w0, true);
  int w1 = __builtin_amdgcn_cvt_pk_fp8_f32(b.x, b.y, 0, false);
  w1 = __builtin_amdgcn_cvt_pk_fp8_f32(b.z, b.w, w1, true);
  q.x = (uint)w0;
  q.y = (uint)w1;
  *reinterpret_cast<uint2*>(out8 + (size_t)i * 8) = q;
}

// prep weights: Wt1[n][k0..255] = [Ws1;Wn1]^T ; Wt2cat[n][k0..127]:
// n<64 -> Wn2[k][n] (p2 half), n>=64 -> Ws2[k][n-64] (s2 half).
__global__ __launch_bounds__(256) void k_prep_w(const float* __restrict__ Ws1,
                                                const float* __restrict__ Wn1,
                                                const float* __restrict__ Ws2,
                                                const float* __restrict__ Wn2,
                                                ushort* __restrict__ Wt1,
                                                ushort* __restrict__ Wt2cat) {
  int idx = blockIdx.x * 256 + threadIdx.x;
  if (idx < 128 * 256) {
    int n = idx >> 8, k = idx & 255;
    float v = (k < 128) ? Ws1[(size_t)k * 128 + n] : Wn1[(size_t)(k - 128) * 128 + n];
    Wt1[idx] = f2bf(v);
  } else if (idx < 128 * 256 + 128 * 128) {
    int j = idx - 128 * 256;
    int n = j >> 7, k = j & 127;
    float v = (n < 64) ? Wn2[(size_t)k * 64 + n] : Ws2[(size_t)k * 64 + (n - 64)];
    Wt2cat[j] = f2bf(v);
  }
}

#define ACC16(v)                                                               \
  do {                                                                         \
    f32x2 f;                                                                   \
    f = __builtin_amdgcn_cvt_pk_f32_fp8((int)(v).x, false); a[0] += f.x; a[1] += f.y;  \
    f = __builtin_amdgcn_cvt_pk_f32_fp8((int)(v).x, true);  a[2] += f.x; a[3] += f.y;  \
    f = __builtin_amdgcn_cvt_pk_f32_fp8((int)(v).y, false); a[4] += f.x; a[5] += f.y;  \
    f = __builtin_amdgcn_cvt_pk_f32_fp8((int)(v).y, true);  a[6] += f.x; a[7] += f.y;  \
    f = __builtin_amdgcn_cvt_pk_f32_fp8((int)(v).z, false); a[8] += f.x; a[9] += f.y;  \
    f = __builtin_amdgcn_cvt_pk_f32_fp8((int)(v).z, true);  a[10] += f.x; a[11] += f.y;\
    f = __builtin_amdgcn_cvt_pk_f32_fp8((int)(v).w, false); a[12] += f.x; a[13] += f.y;\
    f = __builtin_amdgcn_cvt_pk_f32_fp8((int)(v).w, true);  a[14] += f.x; a[15] += f.y;\
  } while (0)

// -------- layer-1 aggregate: fp8 128B rows; 8-lane group per node ---------
__global__ __launch_bounds__(256) void k_agg1(const uchar* __restrict__ X8,
                                              const int* __restrict__ col,
                                              const int* __restrict__ rs,
                                              const int* __restrict__ deg,
                                              ushort* __restrict__ outb, int n) {
  int node = blockIdx.x * 32 + (threadIdx.x >> 3);
  if (node >= n) return;
  int sl = threadIdx.x & 7;
  int gbase = (threadIdx.x & 63) & ~7;
  int r0 = rs[node], d = deg[node];
  float a[16] = {};
  int j = 0;
  while (j < d) {
    int cnt = min(d - j, 8);
    int myc = (sl < cnt) ? col[r0 + j + sl] : 0;
    int jj = 0;
    for (; jj + 4 <= cnt; jj += 4) {
      int c0 = __shfl(myc, gbase + jj + 0, 64);
      int c1 = __shfl(myc, gbase + jj + 1, 64);
      int c2 = __shfl(myc, gbase + jj + 2, 64);
      int c3 = __shfl(myc, gbase + jj + 3, 64);
      uint4 v0 = *reinterpret_cast<const uint4*>(X8 + (size_t)c0 * 128 + sl * 16);
      uint4 v1 = *reinterpret_cast<const uint4*>(X8 + (size_t)c1 * 128 + sl * 16);
      uint4 v2 = *reinterpret_cast<const uint4*>(X8 + (size_t)c2 * 128 + sl * 16);
      uint4 v3 = *reinterpret_cast<const uint4*>(X8 + (size_t)c3 * 128 + sl * 16);
      { uint4 v = v0; ACC16(v); }
      { uint4 v = v1; ACC16(v); }
      { uint4 v = v2; ACC16(v); }
      { uint4 v = v3; ACC16(v); }
    }
    for (; jj < cnt; jj++) {
      int c0 = __shfl(myc, gbase + jj, 64);
      uint4 v = *reinterpret_cast<const uint4*>(X8 + (size_t)c0 * 128 + sl * 16);
      ACC16(v);
    }
    j += cnt;
  }
  float rinv = 1.0f / fmaxf((float)d, 1.0f);
  ushort o[16];
#pragma unroll
  for (int k = 0; k < 16; k++) o[k] = f2bf(a[k] * rinv);
  ulonglong2* dst = reinterpret_cast<ulonglong2*>(outb + (size_t)node * 128 + sl * 16);
  dst[0] = reinterpret_cast<ulonglong2*>(o)[0];
  dst[1] = reinterpret_cast<ulonglong2*>(o)[1];
}

// -------- layer-2 fused gather+add: fp8 64B rows; 4-lane group per node ----
__global__ __launch_bounds__(256) void k_agg_out(const uchar* __restrict__ P8,
                                                 const float* __restrict__ S,
                                                 const int* __restrict__ col,
                                                 const int* __restrict__ rs,
                                                 const int* __restrict__ deg,
                                                 float* __restrict__ out, int n) {
  int node = blockIdx.x * 64 + (threadIdx.x >> 2);
  if (node >= n) return;
  int sl = threadIdx.x & 3;
  int gbase = (threadIdx.x & 63) & ~3;
  int r0 = rs[node], d = deg[node];
  float a[16] = {};
  int j = 0;
  while (j < d) {
    int cnt = min(d - j, 4);
    int myc = (sl < cnt) ? col[r0 + j + sl] : 0;
    int jj = 0;
    for (; jj + 4 <= cnt; jj += 4) {
      int c0 = __shfl(myc, gbase + 0, 64);
      int c1 = __shfl(myc, gbase + 1, 64);
      int c2 = __shfl(myc, gbase + 2, 64);
      int c3 = __shfl(myc, gbase + 3, 64);
      uint4 v0 = *reinterpret_cast<const uint4*>(P8 + (size_t)c0 * 64 + sl * 16);
      uint4 v1 = *reinterpret_cast<const uint4*>(P8 + (size_t)c1 * 64 + sl * 16);
      uint4 v2 = *reinterpret_cast<const uint4*>(P8 + (size_t)c2 * 64 + sl * 16);
      uint4 v3 = *reinterpret_cast<const uint4*>(P8 + (size_t)c3 * 64 + sl * 16);
      { uint4 v = v0; ACC16(v); }
      { uint4 v = v1; ACC16(v); }
      { uint4 v = v2; ACC16(v); }
      { uint4 v = v3; ACC16(v); }
    }
    for (; jj < cnt; jj++) {
      int c0 = __shfl(myc, gbase + jj, 64);
      uint4 v = *reinterpret_cast<const uint4*>(P8 + (size_t)c0 * 64 + sl * 16);
      ACC16(v);
    }
    j += cnt;
  }
  float rinv = 1.0f / fmaxf((float)d, 1.0f);
  const float4* sp = reinterpret_cast<const float4*>(S + (size_t)node * 64 + sl * 16);
  float4* op = reinterpret_cast<float4*>(out + (size_t)node * 64 + sl * 16);
#pragma unroll
  for (int q = 0; q < 4; q++) {
    float4 s = sp[q];
    float4 o;
    o.x = fmaxf(a[q * 4 + 0] * rinv + s.x, 0.f);
    o.y = fmaxf(a[q * 4 + 1] * rinv + s.y, 0.f);
    o.z = fmaxf(a[q * 4 + 2] * rinv + s.z, 0.f);
    o.w = fmaxf(a[q * 4 + 3] * rinv + s.w, 0.f);
    op[q] = o;
  }
}

// ---------------- PERSISTENT fused GEMM v2 ----------------
// 256 blocks x 512 thr (8 waves: wn in {0,1} node-half, wj in 0..3 j-quarter).
// BM=128 nodes. A=W frags (lane&15=j), B=X/h1 frags (lane&15=node) ->
// C: lane&15=node, row-quad = 4 consecutive j -> vectorized epilogues.
__global__ __launch_bounds__(512, 2) void k_persist(
    const ushort* __restrict__ Xb, const ushort* __restrict__ Gb,
    const ushort* __restrict__ Wt1, const ushort* __restrict__ Wt2,
    const float* __restrict__ b1, const float* __restrict__ b2,
    uchar* __restrict__ P8, float* __restrict__ S2, int M, int ntiles) {
  __shared__ ushort W1s[128 * 256];  // 64 KB: [j][512B], granule ^ (j&15)
  __shared__ char Xs[128 * 512];     // 64 KB: X tile [node][512B]; h1 overlay 32KB

  const int t = threadIdx.x;
  const int lane = t & 63;
  const int w = t >> 6;
  const int wn = w & 1;   // node half (64 nodes)
  const int wj = w >> 1;  // j quarter (32 features)
  const int l15 = lane & 15;
  const int grp = lane >> 4;

  // ---- stage W1 once (source pre-swizzled -> linear LDS) ----
#pragma unroll
  for (int i = 0; i < 8; i++) {
    int g = t + 512 * i;
    int row = g >> 5, slot = g & 31;
    const ushort* src = Wt1 + (size_t)row * 256 + ((slot ^ (row & 15)) << 3);
    char* dst = (char*)W1s + ((size_t)(512 * i + (t & ~63)) << 4);
    GLDS(src, dst);
  }

  // ---- W2 fragments in registers (persistent) ----
  short8 w2f[2][4];
#pragma unroll
  for (int fm = 0; fm < 2; fm++)
#pragma unroll
    for (int ks = 0; ks < 4; ks++) {
      int j2 = wj * 32 + fm * 16 + l15;
      int gk = ks * 4 + grp;
      w2f[fm][ks] =
          *reinterpret_cast<const short8*>(Wt2 + (size_t)j2 * 128 + gk * 8);
    }

  // ---- bias quads (j0 = this thread's 4 consecutive output features) ----
  float4 bb1q[2], bb2q[2];
#pragma unroll
  for (int fm = 0; fm < 2; fm++) {
    int j0 = wj * 32 + fm * 16 + grp * 4;
    bb1q[fm] = *reinterpret_cast<const float4*>(b1 + j0);
    bb2q[fm] = (wj >= 2) ? *reinterpret_cast<const float4*>(b2 + j0 - 64)
                         : make_float4(0.f, 0.f, 0.f, 0.f);
  }

  int tile = blockIdx.x;
  if (tile >= ntiles) return;

  uint4 xr[8];
  auto LOADX = [&](int tl) {
#pragma unroll
    for (int i = 0; i < 8; i++) {
      int g = t + 512 * i;
      int row = g >> 5, slot = g & 31;
      int kk = slot ^ (row & 15);
      int gm = min(tl * 128 + row, M - 1);
      const ushort* s = (kk < 16) ? Xb + (size_t)gm * 128 + kk * 8
                                  : Gb + (size_t)gm * 128 + (kk - 16) * 8;
      xr[i] = *reinterpret_cast<const uint4*>(s);
    }
  };
  auto WRITEX = [&]() {
#pragma unroll
    for (int i = 0; i < 8; i++)
      *reinterpret_cast<uint4*>(Xs + (size_t)(t + 512 * i) * 16) = xr[i];
  };

  LOADX(tile);
  WRITEX();        // implicit vmcnt waits on xr deps
  __syncthreads(); // W1s + Xs(0) visible (full drain)

  while (true) {
    int next = tile + gridDim.x;
    bool more = (next < ntiles);
    if (more) LOADX(next);  // prefetch hidden under both GEMMs

    // ---- GEMM1: D1[j][node], K=256; A=W1s frags, B=Xs frags ----
    f32x4 acc1[2][4] = {};
#pragma unroll
    for (int ks = 0; ks < 8; ks++) {
      int ga = ks * 4 + grp;
      short8 af[2], bf[4];
#pragma unroll
      for (int fm = 0; fm < 2; fm++) {
        int j = wj * 32 + fm * 16 + l15;
        af[fm] = *reinterpret_cast<const short8*>(
            (char*)W1s + j * 512 + ((ga ^ (j & 15)) << 4));
      }
#pragma unroll
      for (int fn = 0; fn < 4; fn++) {
        int node = wn * 64 + fn * 16 + l15;
        bf[fn] = *reinterpret_cast<const short8*>(
            Xs + node * 512 + ((ga ^ (node & 15)) << 4));
      }
#pragma unroll
      for (int fm = 0; fm < 2; fm++)
#pragma unroll
        for (int fn = 0; fn < 4; fn++)
          acc1[fm][fn] = __builtin_amdgcn_mfma_f32_16x16x32_bf16(
              af[fm], bf[fn], acc1[fm][fn], 0, 0, 0);
    }

    __builtin_amdgcn_s_barrier();  // all Xs reads done (WAR before h1 write)
    FENCE();

    // ---- epi1: h1[node][j] = relu(acc1+b1) -> Xs overlay, b64 writes ----
#pragma unroll
    for (int fm = 0; fm < 2; fm++) {
      int j0 = wj * 32 + fm * 16 + grp * 4;
      int G = j0 >> 3, hf = (j0 >> 2) & 1;
#pragma unroll
      for (int fn = 0; fn < 4; fn++) {
        int node = wn * 64 + fn * 16 + l15;
        ushort q[4];
#pragma unroll
        for (int r = 0; r < 4; r++)
          q[r] = f2bf(
              fmaxf(acc1[fm][fn][r] + ((const float*)&bb1q[fm])[r], 0.f));
        *reinterpret_cast<unsigned long long*>(
            Xs + node * 256 + ((G ^ (node & 15)) << 4) + hf * 8) =
            *reinterpret_cast<unsigned long long*>(q);
      }
    }
    LGKM0();
    __builtin_amdgcn_s_barrier();  // h1 visible
    FENCE();

    // ---- GEMM2: D2[j2][node], K=128; A=w2f regs, B=h1 frags (LDS) ----
    f32x4 acc2[2][4] = {};
#pragma unroll
    for (int ks = 0; ks < 4; ks++) {
      int gk = ks * 4 + grp;
      short8 bf[4];
#pragma unroll
      for (int fn = 0; fn < 4; fn++) {
        int node = wn * 64 + fn * 16 + l15;
        bf[fn] = *reinterpret_cast<const short8*>(
            Xs + node * 256 + ((gk ^ (node & 15)) << 4));
      }
#pragma unroll
      for (int fm = 0; fm < 2; fm++)
#pragma unroll
        for (int fn = 0; fn < 4; fn++)
          acc2[fm][fn] = __builtin_amdgcn_mfma_f32_16x16x32_bf16(
              w2f[fm][ks], bf[fn], acc2[fm][fn], 0, 0, 0);
    }

    // ---- epi2: wj<2 -> p8 (u32 of 4 fp8); wj>=2 -> s2 (float4 + b2) ----
#pragma unroll
    for (int fm = 0; fm < 2; fm++) {
      int j0 = wj * 32 + fm * 16 + grp * 4;
#pragma unroll
      for (int fn = 0; fn < 4; fn++) {
        int ng = tile * 128 + wn * 64 + fn * 16 + l15;
        if (ng < M) {
          if (wj < 2) {
            int p = __builtin_amdgcn_cvt_pk_fp8_f32(acc2[fm][fn][0],
                                                    acc2[fm][fn][1], 0, false);
            p = __builtin_amdgcn_cvt_pk_fp8_f32(acc2[fm][fn][2],
                                                acc2[fm][fn][3], p, true);
            *reinterpret_cast<uint*>(P8 + (size_t)ng * 64 + j0) = (uint)p;
          } else {
            float4 v;
            v.x = acc2[fm][fn][0] + bb2q[fm].x;
            v.y = acc2[fm][fn][1] + bb2q[fm].y;
            v.z = acc2[fm][fn][2] + bb2q[fm].z;
            v.w = acc2[fm][fn][3] + bb2q[fm].w;
            *reinterpret_cast<float4*>(S2 + (size_t)ng * 64 + (j0 - 64)) = v;
          }
        }
      }
    }

    if (!more) break;
    __builtin_amdgcn_s_barrier();  // h1 reads done (WAR before X overwrite)
    FENCE();
    WRITEX();                      // implicit vmcnt waits on prefetch regs
    LGKM0();
    __builtin_amdgcn_s_barrier();  // X(next) visible
    FENCE();
    tile = next;
  }
}

extern "C" void kernel_launch(void* const* d_in, const int* in_sizes, int n_in,
                              void* d_out, int out_size, void* d_ws, size_t ws_size,
                              hipStream_t stream) {
  const float* h = (const float*)d_in[0];
  const int* esrc = (const int*)d_in[1];
  const int* edst = (const int*)d_in[2];
  const float* Ws1 = (const float*)d_in[3];
  const float* Wn1 = (const float*)d_in[4];
  const float* b1 = (const float*)d_in[5];
  const float* Ws2 = (const float*)d_in[6];
  const float* Wn2 = (const float*)d_in[7];
  const float* b2 = (const float*)d_in[8];
  float* out = (float*)d_out;

  const int N = in_sizes[0] / 128;  // 100000
  const int E = in_sizes[1];        // 1600000
  const int P = (N + 255) >> 8;     // 391 buckets (<=512)

  char* base = (char*)d_ws;
  size_t off = 0;
  auto alloc = [&](size_t bytes) {
    size_t o = off;
    off += (bytes + 255) & ~(size_t)255;
    return o;
  };
  int* deg = (int*)(base + alloc((size_t)N * 4));
  int* rs = (int*)(base + alloc((size_t)N * 4));
  int* bcnt = (int*)(base + alloc(513 * 4));
  int* bbase = (int*)(base + alloc(513 * 4));
  int* bcur = (int*)(base + alloc(513 * 4));
  uint* bed = (uint*)(base + alloc((size_t)E * 4));
  int* col = (int*)(base + alloc((size_t)E * 4));
  ushort* hb = (ushort*)(base + alloc((size_t)N * 128 * 2));
  uchar* h8 = (uchar*)(base + alloc((size_t)N * 128));
  ushort* aggb = (ushort*)(base + alloc((size_t)N * 128 * 2));
  ushort* Wt1 = (ushort*)(base + alloc(128 * 256 * 2));
  ushort* Wt2cat = (ushort*)(base + alloc(128 * 128 * 2));
  // overlays:
  uchar* p8 = (uchar*)bed;   // [N][64] fp8: bed dead after k_bcsr; N*64 <= E*4
  float* s2f = (float*)aggb; // [N][64] f32: tile-local rows, read-before-write

  const int NCH = (E + 8191) / 8192;
  const int NT = (N + 127) / 128;  // 782 M-tiles

  (void)hipMemsetAsync(bcnt, 0, 513 * 4, stream);
  k_bhist<<<NCH, 256, 0, stream>>>(edst, bcnt, E);
  k_bscan<<<1, 512, 0, stream>>>(bcnt, bbase, bcur, P, E);
  k_bscatter<<<NCH, 256, 0, stream>>>(edst, esrc, bcur, bed, E, P);
  k_bcsr<<<P, 256, 0, stream>>>(bed, bbase, deg, rs, col, N);

  k_prep_w<<<((128 * 256 + 128 * 128) + 255) / 256, 256, 0, stream>>>(
      Ws1, Wn1, Ws2, Wn2, Wt1, Wt2cat);
  k_cast<<<((N * 128 / 8) + 255) / 256, 256, 0, stream>>>(h, hb, h8, N * 128 / 8);

  // Layer 1 aggregate, then persistent fused GEMM1+GEMM2 -> p2 (fp8) + s2 (f32)
  k_agg1<<<(N + 31) / 32, 256, 0, stream>>>(h8, col, rs, deg, aggb, N);
  k_persist<<<256, 512, 0, stream>>>(hb, aggb, Wt1, Wt2cat, b1, b2, p8, s2f, N, NT);
  // Layer 2 fused gather + add + relu
  k_agg_out<<<(N + 63) / 64, 256, 0, stream>>>(p8, s2f, col, rs, deg, out, N);
}

// Round 15
// 165.228 us; speedup vs baseline: 1.1940x; 1.1940x over previous
//
#include <hip/hip_runtime.h>

// GraphSAGE 2-layer (mean agg), N=100K, E=1.6M, 128->128->64, f32 in/out.
// R15 = R11 config (persist-v1, no degree sort) + deeper gather MLP:
// agg kernels batch ALL 8 chunk row-loads before converting (2x loads in
// flight vs R11's 4+convert alternation). cast+prep_w merged (1 launch).
// R14 lesson: operand-swapped GEMM fixed LDS conflicts but scattered the
// global stores (WRITE 31->81MB) -- net loss; v1 epilogue layout restored.
// Overlays: p8->bed (dead after CSR), s2f->aggb (tile-local rows, WAR-safe).

typedef __attribute__((ext_vector_type(8))) short short8;
typedef __attribute__((ext_vector_type(4))) float f32x4;
typedef __attribute__((ext_vector_type(2))) float f32x2;

__device__ __forceinline__ ushort f2bf(float f) {
  uint u = __float_as_uint(f);
  u += 0x7fffu + ((u >> 16) & 1u);  // round-to-nearest-even
  return (ushort)(u >> 16);
}

#define GLDS(src, dst)                                                        \
  __builtin_amdgcn_global_load_lds(                                           \
      (const __attribute__((address_space(1))) void*)(src),                   \
      (__attribute__((address_space(3))) void*)(dst), 16, 0, 0)

#define FENCE() asm volatile("" ::: "memory")
#define LGKM0() asm volatile("s_waitcnt lgkmcnt(0)" ::: "memory")

// ================= bucketed CSR build =================
__global__ __launch_bounds__(256) void k_bhist(const int* __restrict__ dst,
                                               int* __restrict__ bcnt, int E) {
  __shared__ int h[512];
  int t = threadIdx.x;
  for (int i = t; i < 512; i += 256) h[i] = 0;
  __syncthreads();
  int base = blockIdx.x * 8192;
  int end = min(base + 8192, E);
  for (int e = base + t; e < end; e += 256)
    atomicAdd(&h[((uint)dst[e]) >> 8], 1);
  __syncthreads();
  for (int i = t; i < 512; i += 256)
    if (h[i]) atomicAdd(&bcnt[i], h[i]);
}

__global__ __launch_bounds__(512) void k_bscan(const int* __restrict__ bcnt,
                                               int* __restrict__ bbase,
                                               int* __restrict__ bcur, int P, int E) {
  __shared__ int s[512];
  int t = threadIdx.x;
  int v = (t < P) ? bcnt[t] : 0;
  s[t] = v;
  __syncthreads();
  for (int off = 1; off < 512; off <<= 1) {
    int x = (t >= off) ? s[t - off] : 0;
    __syncthreads();
    s[t] += x;
    __syncthreads();
  }
  int ex = s[t] - v;
  if (t < P) {
    bbase[t] = ex;
    bcur[t] = ex;
  }
  if (t == P - 1) bbase[P] = E;
}

__global__ __launch_bounds__(256) void k_bscatter(const int* __restrict__ dst,
                                                  const int* __restrict__ src,
                                                  int* __restrict__ bcur,
                                                  uint* __restrict__ bed, int E, int P) {
  __shared__ int hist[512];
  __shared__ int incl[512];
  __shared__ int gpos[512];
  __shared__ int cur[512];
  __shared__ uint stage[8192];
  __shared__ ushort bof[8192];
  int t = threadIdx.x;
  int base = blockIdx.x * 8192;
  int cnt = min(8192, E - base);
  for (int i = t; i < 512; i += 256) hist[i] = 0;
  __syncthreads();
  for (int i = t; i < cnt; i += 256)
    atomicAdd(&hist[((uint)dst[base + i]) >> 8], 1);
  __syncthreads();
  incl[t] = hist[t];
  incl[t + 256] = hist[t + 256];
  __syncthreads();
  for (int off = 1; off < 512; off <<= 1) {
    int i0 = t, i1 = t + 256;
    int a0 = (i0 >= off) ? incl[i0 - off] : 0;
    int a1 = (i1 >= off) ? incl[i1 - off] : 0;
    __syncthreads();
    incl[i0] += a0;
    incl[i1] += a1;
    __syncthreads();
  }
  cur[t] = incl[t] - hist[t];
  cur[t + 256] = incl[t + 256] - hist[t + 256];
  for (int i = t; i < P; i += 256)
    if (hist[i]) gpos[i] = atomicAdd(&bcur[i], hist[i]);
  __syncthreads();
  for (int i = t; i < cnt; i += 256) {
    int d = dst[base + i];
    int b = ((uint)d) >> 8;
    uint val = (((uint)src[base + i]) << 8) | (uint)(d & 255);
    int slot = atomicAdd(&cur[b], 1);
    stage[slot] = val;
    bof[slot] = (ushort)b;
  }
  __syncthreads();
  for (int i = t; i < cnt; i += 256) {
    int b = bof[i];
    int ex = incl[b] - hist[b];
    bed[gpos[b] + (i - ex)] = stage[i];
  }
}

__global__ __launch_bounds__(256) void k_bcsr(const uint* __restrict__ bed,
                                              const int* __restrict__ bbase,
                                              int* __restrict__ deg,
                                              int* __restrict__ rs,
                                              int* __restrict__ col, int N) {
  __shared__ int dcnt[256];
  __shared__ int sofs[256];
  int b = blockIdx.x, t = threadIdx.x;
  int e0 = bbase[b], e1 = bbase[b + 1];
  dcnt[t] = 0;
  __syncthreads();
  for (int e = e0 + t; e < e1; e += 256) atomicAdd(&dcnt[bed[e] & 255u], 1);
  __syncthreads();
  int v0 = dcnt[t];
  sofs[t] = v0;
  __syncthreads();
  for (int off = 1; off < 256; off <<= 1) {
    int x = (t >= off) ? sofs[t - off] : 0;
    __syncthreads();
    sofs[t] += x;
    __syncthreads();
  }
  int ex = sofs[t] - v0;
  int node = (b << 8) + t;
  if (node < N) {
    deg[node] = v0;
    rs[node] = e0 + ex;
  }
  __syncthreads();
  dcnt[t] = e0 + ex;
  __syncthreads();
  for (int e = e0 + t; e < e1; e += 256) {
    uint v = bed[e];
    int pos = atomicAdd(&dcnt[v & 255u], 1);
    col[pos] = (int)(v >> 8);
  }
}

// -------- merged prep: cast h -> {bf16 hb, fp8 h8}; transpose W -> Wt1/Wt2cat
__global__ __launch_bounds__(256) void k_prep(
    const float* __restrict__ in, const float* __restrict__ Ws1,
    const float* __restrict__ Wn1, const float* __restrict__ Ws2,
    const float* __restrict__ Wn2, ushort* __restrict__ outb,
    uchar* __restrict__ out8, ushort* __restrict__ Wt1,
    ushort* __restrict__ Wt2cat, int n8, int CB) {
  if ((int)blockIdx.x < CB) {
    int i = blockIdx.x * 256 + threadIdx.x;
    if (i >= n8) return;
    const float4* p = reinterpret_cast<const float4*>(in) + i * 2;
    float4 a = p[0], b = p[1];
    ushort u[8];
    u[0] = f2bf(a.x); u[1] = f2bf(a.y); u[2] = f2bf(a.z); u[3] = f2bf(a.w);
    u[4] = f2bf(b.x); u[5] = f2bf(b.y); u[6] = f2bf(b.z); u[7] = f2bf(b.w);
    *reinterpret_cast<ulonglong2*>(outb + (size_t)i * 8) =
        *reinterpret_cast<ulonglong2*>(u);
    uint2 q;
    int w0 = __builtin_amdgcn_cvt_pk_fp8_f32(a.x, a.y, 0, false);
    w0 = __builtin_amdgcn_cvt_pk_fp8_f32(a.z, a.w, w0, true);
    int w1 = __builtin_amdgcn_cvt_pk_fp8_f32(b.x, b.y, 0, false);
    w1 = __builtin_amdgcn_cvt_pk_fp8_f32(b.z, b.w, w1, true);
    q.x = (uint)w0;
    q.y = (uint)w1;
    *reinterpret_cast<uint2*>(out8 + (size_t)i * 8) = q;
  } else {
    int idx = ((int)blockIdx.x - CB) * 256 + threadIdx.x;
    if (idx < 128 * 256) {
      int n = idx >> 8, k = idx & 255;
      float v = (k < 128) ? Ws1[(size_t)k * 128 + n]
                          : Wn1[(size_t)(k - 128) * 128 + n];
      Wt1[idx] = f2bf(v);
    } else if (idx < 128 * 256 + 128 * 128) {
      int j = idx - 128 * 256;
      int n = j >> 7, k = j & 127;
      float v = (n < 64) ? Wn2[(size_t)k * 64 + n] : Ws2[(size_t)k * 64 + (n - 64)];
      Wt2cat[j] = f2bf(v);
    }
  }
}

#define ACC16(v)                                                               \
  do {                                                                         \
    f32x2 f;                                                                   \
    f = __builtin_amdgcn_cvt_pk_f32_fp8((int)(v).x, false); a[0] += f.x; a[1] += f.y;  \
    f = __builtin_amdgcn_cvt_pk_f32_fp8((int)(v).x, true);  a[2] += f.x; a[3] += f.y;  \
    f = __builtin_amdgcn_cvt_pk_f32_fp8((int)(v).y, false); a[4] += f.x; a[5] += f.y;  \
    f = __builtin_amdgcn_cvt_pk_f32_fp8((int)(v).y, true);  a[6] += f.x; a[7] += f.y;  \
    f = __builtin_amdgcn_cvt_pk_f32_fp8((int)(v).z, false); a[8] += f.x; a[9] += f.y;  \
    f = __builtin_amdgcn_cvt_pk_f32_fp8((int)(v).z, true);  a[10] += f.x; a[11] += f.y;\
    f = __builtin_amdgcn_cvt_pk_f32_fp8((int)(v).w, false); a[12] += f.x; a[13] += f.y;\
    f = __builtin_amdgcn_cvt_pk_f32_fp8((int)(v).w, true);  a[14] += f.x; a[15] += f.y;\
  } while (0)

// -------- layer-1 aggregate: fp8 128B rows; 8-lane group per node ---------
// Chunk of 8 neighbors: issue ALL 8 row loads (dwordx4, independent), then
// convert. Guards are group-uniform (cnt identical across group); shfls
// executed unconditionally by the whole group (sources always active).
__global__ __launch_bounds__(256) void k_agg1(const uchar* __restrict__ X8,
                                              const int* __restrict__ col,
                                              const int* __restrict__ rs,
                                              const int* __restrict__ deg,
                                              ushort* __restrict__ outb, int n) {
  int node = blockIdx.x * 32 + (threadIdx.x >> 3);
  if (node >= n) return;
  int sl = threadIdx.x & 7;
  int gbase = (threadIdx.x & 63) & ~7;
  int r0 = rs[node], d = deg[node];
  float a[16] = {};
  int j = 0;
  while (j < d) {
    int cnt = min(d - j, 8);
    int myc = (sl < cnt) ? col[r0 + j + sl] : 0;
    int c0 = __shfl(myc, gbase + 0, 64);
    int c1 = __shfl(myc, gbase + 1, 64);
    int c2 = __shfl(myc, gbase + 2, 64);
    int c3 = __shfl(myc, gbase + 3, 64);
    int c4 = __shfl(myc, gbase + 4, 64);
    int c5 = __shfl(myc, gbase + 5, 64);
    int c6 = __shfl(myc, gbase + 6, 64);
    int c7 = __shfl(myc, gbase + 7, 64);
    uint4 v0, v1, v2, v3, v4, v5, v6, v7;
    // all loads issued before any conversion -> 8 in flight per lane
    if (cnt > 0) v0 = *reinterpret_cast<const uint4*>(X8 + (size_t)c0 * 128 + sl * 16);
    if (cnt > 1) v1 = *reinterpret_cast<const uint4*>(X8 + (size_t)c1 * 128 + sl * 16);
    if (cnt > 2) v2 = *reinterpret_cast<const uint4*>(X8 + (size_t)c2 * 128 + sl * 16);
    if (cnt > 3) v3 = *reinterpret_cast<const uint4*>(X8 + (size_t)c3 * 128 + sl * 16);
    if (cnt > 4) v4 = *reinterpret_cast<const uint4*>(X8 + (size_t)c4 * 128 + sl * 16);
    if (cnt > 5) v5 = *reinterpret_cast<const uint4*>(X8 + (size_t)c5 * 128 + sl * 16);
    if (cnt > 6) v6 = *reinterpret_cast<const uint4*>(X8 + (size_t)c6 * 128 + sl * 16);
    if (cnt > 7) v7 = *reinterpret_cast<const uint4*>(X8 + (size_t)c7 * 128 + sl * 16);
    if (cnt > 0) ACC16(v0);
    if (cnt > 1) ACC16(v1);
    if (cnt > 2) ACC16(v2);
    if (cnt > 3) ACC16(v3);
    if (cnt > 4) ACC16(v4);
    if (cnt > 5) ACC16(v5);
    if (cnt > 6) ACC16(v6);
    if (cnt > 7) ACC16(v7);
    j += cnt;
  }
  float rinv = 1.0f / fmaxf((float)d, 1.0f);
  ushort o[16];
#pragma unroll
  for (int k = 0; k < 16; k++) o[k] = f2bf(a[k] * rinv);
  ulonglong2* dst = reinterpret_cast<ulonglong2*>(outb + (size_t)node * 128 + sl * 16);
  dst[0] = reinterpret_cast<ulonglong2*>(o)[0];
  dst[1] = reinterpret_cast<ulonglong2*>(o)[1];
}

// -------- layer-2 fused gather+add: fp8 64B rows; 4-lane group per node ----
// Chunk of 8 (two index regs), all 8 loads in flight before converting.
__global__ __launch_bounds__(256) void k_agg_out(const uchar* __restrict__ P8,
                                                 const float* __restrict__ S,
                                                 const int* __restrict__ col,
                                                 const int* __restrict__ rs,
                                                 const int* __restrict__ deg,
                                                 float* __restrict__ out, int n) {
  int node = blockIdx.x * 64 + (threadIdx.x >> 2);
  if (node >= n) return;
  int sl = threadIdx.x & 3;
  int gbase = (threadIdx.x & 63) & ~3;
  int r0 = rs[node], d = deg[node];
  float a[16] = {};
  int j = 0;
  while (j < d) {
    int cnt = min(d - j, 8);
    int myc0 = (sl < cnt) ? col[r0 + j + sl] : 0;
    int myc1 = (sl + 4 < cnt) ? col[r0 + j + 4 + sl] : 0;
    int c0 = __shfl(myc0, gbase + 0, 64);
    int c1 = __shfl(myc0, gbase + 1, 64);
    int c2 = __shfl(myc0, gbase + 2, 64);
    int c3 = __shfl(myc0, gbase + 3, 64);
    int c4 = __shfl(myc1, gbase + 0, 64);
    int c5 = __shfl(myc1, gbase + 1, 64);
    int c6 = __shfl(myc1, gbase + 2, 64);
    int c7 = __shfl(myc1, gbase + 3, 64);
    uint4 v0, v1, v2, v3, v4, v5, v6, v7;
    if (cnt > 0) v0 = *reinterpret_cast<const uint4*>(P8 + (size_t)c0 * 64 + sl * 16);
    if (cnt > 1) v1 = *reinterpret_cast<const uint4*>(P8 + (size_t)c1 * 64 + sl * 16);
    if (cnt > 2) v2 = *reinterpret_cast<const uint4*>(P8 + (size_t)c2 * 64 + sl * 16);
    if (cnt > 3) v3 = *reinterpret_cast<const uint4*>(P8 + (size_t)c3 * 64 + sl * 16);
    if (cnt > 4) v4 = *reinterpret_cast<const uint4*>(P8 + (size_t)c4 * 64 + sl * 16);
    if (cnt > 5) v5 = *reinterpret_cast<const uint4*>(P8 + (size_t)c5 * 64 + sl * 16);
    if (cnt > 6) v6 = *reinterpret_cast<const uint4*>(P8 + (size_t)c6 * 64 + sl * 16);
    if (cnt > 7) v7 = *reinterpret_cast<const uint4*>(P8 + (size_t)c7 * 64 + sl * 16);
    if (cnt > 0) ACC16(v0);
    if (cnt > 1) ACC16(v1);
    if (cnt > 2) ACC16(v2);
    if (cnt > 3) ACC16(v3);
    if (cnt > 4) ACC16(v4);
    if (cnt > 5) ACC16(v5);
    if (cnt > 6) ACC16(v6);
    if (cnt > 7) ACC16(v7);
    j += cnt;
  }
  float rinv = 1.0f / fmaxf((float)d, 1.0f);
  const float4* sp = reinterpret_cast<const float4*>(S + (size_t)node * 64 + sl * 16);
  float4* op = reinterpret_cast<float4*>(out + (size_t)node * 64 + sl * 16);
#pragma unroll
  for (int q = 0; q < 4; q++) {
    float4 s = sp[q];
    float4 o;
    o.x = fmaxf(a[q * 4 + 0] * rinv + s.x, 0.f);
    o.y = fmaxf(a[q * 4 + 1] * rinv + s.y, 0.f);
    o.z = fmaxf(a[q * 4 + 2] * rinv + s.z, 0.f);
    o.w = fmaxf(a[q * 4 + 3] * rinv + s.w, 0.f);
    op[q] = o;
  }
}

// ---------------- PERSISTENT fused GEMM (v1, R11-proven) ----------------
__global__ __launch_bounds__(512) void k_persist(const ushort* __restrict__ Xb,
                                                 const ushort* __restrict__ Gb,
                                                 const ushort* __restrict__ Wt1,
                                                 const ushort* __restrict__ Wt2,
                                                 const float* __restrict__ b1,
                                                 const float* __restrict__ b2,
                                                 uchar* __restrict__ P8,
                                                 float* __restrict__ S2,
                                                 int M, int ntiles) {
  __shared__ ushort W1s[128 * 256];  // 64 KB
  __shared__ ushort W2s[128 * 128];  // 32 KB
  __shared__ char Xs[64 * 256 * 2];  // 32 KB X tile; h1 reuses [0,16KB)

  const int t = threadIdx.x;
  const int lane = t & 63;
  const int w = t >> 6;
  const int wm = w >> 2, wn = w & 3;

#pragma unroll
  for (int i = 0; i < 8; i++) {
    int g = t + 512 * i;
    int row = g >> 5, kph = g & 31;
    const ushort* src = Wt1 + (size_t)row * 256 + ((kph ^ (row & 7)) << 3);
    char* dst = (char*)W1s + ((g & ~63) << 4);
    GLDS(src, dst);
  }
#pragma unroll
  for (int i = 0; i < 4; i++) {
    int g = t + 512 * i;
    int row = g >> 4, kph = g & 15;
    const ushort* src = Wt2 + (size_t)row * 128 + ((kph ^ (row & 7)) << 3);
    char* dst = (char*)W2s + ((g & ~63) << 4);
    GLDS(src, dst);
  }

  float bb1[2], bb2[2];
#pragma unroll
  for (int fn = 0; fn < 2; fn++) {
    int colg = wn * 32 + fn * 16 + (lane & 15);
    bb1[fn] = b1[colg];
    bb2[fn] = (colg >= 64) ? b2[colg - 64] : 0.f;
  }

  int tile = blockIdx.x;
  if (tile >= ntiles) return;

  uint4 xr0, xr1, xr2, xr3;
#define LOADX(tl)                                                              \
  {                                                                            \
    int g, row, kk, gm;                                                        \
    const ushort* s;                                                           \
    g = t;            row = g >> 5; kk = (g & 31) ^ (row & 7);                 \
    gm = min((tl) * 64 + row, M - 1);                                          \
    s = (kk < 16) ? Xb + (size_t)gm * 128 + kk * 8                             \
                  : Gb + (size_t)gm * 128 + (kk - 16) * 8;                     \
    xr0 = *reinterpret_cast<const uint4*>(s);                                  \
    g = t + 512;      row = g >> 5; kk = (g & 31) ^ (row & 7);                 \
    gm = min((tl) * 64 + row, M - 1);                                          \
    s = (kk < 16) ? Xb + (size_t)gm * 128 + kk * 8                             \
                  : Gb + (size_t)gm * 128 + (kk - 16) * 8;                     \
    xr1 = *reinterpret_cast<const uint4*>(s);                                  \
    g = t + 1024;     row = g >> 5; kk = (g & 31) ^ (row & 7);                 \
    gm = min((tl) * 64 + row, M - 1);                                          \
    s = (kk < 16) ? Xb + (size_t)gm * 128 + kk * 8                             \
                  : Gb + (size_t)gm * 128 + (kk - 16) * 8;                     \
    xr2 = *reinterpret_cast<const uint4*>(s);                                  \
    g = t + 1536;     row = g >> 5; kk = (g & 31) ^ (row & 7);                 \
    gm = min((tl) * 64 + row, M - 1);                                          \
    s = (kk < 16) ? Xb + (size_t)gm * 128 + kk * 8                             \
                  : Gb + (size_t)gm * 128 + (kk - 16) * 8;                     \
    xr3 = *reinterpret_cast<const uint4*>(s);                                  \
  }
#define WRITEX()                                                               \
  {                                                                            \
    *reinterpret_cast<uint4*>(Xs + (size_t)t * 16) = xr0;                      \
    *reinterpret_cast<uint4*>(Xs + (size_t)(t + 512) * 16) = xr1;              \
    *reinterpret_cast<uint4*>(Xs + (size_t)(t + 1024) * 16) = xr2;             \
    *reinterpret_cast<uint4*>(Xs + (size_t)(t + 1536) * 16) = xr3;             \
  }

  LOADX(tile);
  WRITEX();
  __syncthreads();

  while (true) {
    int next = tile + gridDim.x;
    bool more = (next < ntiles);
    if (more) LOADX(next);

    f32x4 acc[2][2] = {};
#pragma unroll
    for (int ks = 0; ks < 8; ks++) {
      int ga = ks * 4 + (lane >> 4);
      short8 af[2], bf[2];
#pragma unroll
      for (int fm = 0; fm < 2; fm++) {
        int row = wm * 32 + fm * 16 + (lane & 15);
        af[fm] = *reinterpret_cast<const short8*>(
            Xs + row * 512 + ((ga ^ (row & 7)) << 4));
      }
#pragma unroll
      for (int fn = 0; fn < 2; fn++) {
        int colr = wn * 32 + fn * 16 + (lane & 15);
        bf[fn] = *reinterpret_cast<const short8*>(
            (char*)W1s + colr * 512 + ((ga ^ (colr & 7)) << 4));
      }
#pragma unroll
      for (int fm = 0; fm < 2; fm++)
#pragma unroll
        for (int fn = 0; fn < 2; fn++)
          acc[fm][fn] = __builtin_amdgcn_mfma_f32_16x16x32_bf16(
              af[fm], bf[fn], acc[fm][fn], 0, 0, 0);
    }

    __builtin_amdgcn_s_barrier();
    FENCE();

#pragma unroll
    for (int fn = 0; fn < 2; fn++) {
      int colg = wn * 32 + fn * 16 + (lane & 15);
      int gg = colg >> 3, cb = (colg & 7) * 2;
#pragma unroll
      for (int fm = 0; fm < 2; fm++) {
#pragma unroll
        for (int r = 0; r < 4; r++) {
          int rowl = wm * 32 + fm * 16 + (lane >> 4) * 4 + r;
          ushort hv = f2bf(fmaxf(acc[fm][fn][r] + bb1[fn], 0.f));
          *reinterpret_cast<ushort*>(
              Xs + rowl * 256 + ((gg ^ (rowl & 7)) << 4) + cb) = hv;
        }
      }
    }
    LGKM0();
    __builtin_amdgcn_s_barrier();
    FENCE();

    f32x4 acc2[2][2] = {};
#pragma unroll
    for (int ks = 0; ks < 4; ks++) {
      int gk = ks * 4 + (lane >> 4);
      short8 af[2], bf[2];
#pragma unroll
      for (int fm = 0; fm < 2; fm++) {
        int row = wm * 32 + fm * 16 + (lane & 15);
        af[fm] = *reinterpret_cast<const short8*>(
            Xs + row * 256 + ((gk ^ (row & 7)) << 4));
      }
#pragma unroll
      for (int fn = 0; fn < 2; fn++) {
        int colr = wn * 32 + fn * 16 + (lane & 15);
        bf[fn] = *reinterpret_cast<const short8*>(
            (char*)W2s + colr * 256 + ((gk ^ (colr & 7)) << 4));
      }
#pragma unroll
      for (int fm = 0; fm < 2; fm++)
#pragma unroll
        for (int fn = 0; fn < 2; fn++)
          acc2[fm][fn] = __builtin_amdgcn_mfma_f32_16x16x32_bf16(
              af[fm], bf[fn], acc2[fm][fn], 0, 0, 0);
    }

#pragma unroll
    for (int fn = 0; fn < 2; fn++) {
      int colg = wn * 32 + fn * 16 + (lane & 15);
#pragma unroll
      for (int fm = 0; fm < 2; fm++) {
#pragma unroll
        for (int r = 0; r < 4; r++) {
          int rowg = tile * 64 + wm * 32 + fm * 16 + (lane >> 4) * 4 + r;
          if (rowg >= M) continue;
          if (colg < 64) {
            float v = acc2[fm][fn][r];
            int b8 = __builtin_amdgcn_cvt_pk_fp8_f32(v, v, 0, false);
            P8[(size_t)rowg * 64 + colg] = (uchar)(b8 & 0xff);
          } else {
            S2[(size_t)rowg * 64 + (colg - 64)] = acc2[fm][fn][r] + bb2[fn];
          }
        }
      }
    }

    if (!more) break;
    __builtin_amdgcn_s_barrier();
    FENCE();
    WRITEX();
    LGKM0();
    __builtin_amdgcn_s_barrier();
    FENCE();
    tile = next;
  }
#undef LOADX
#undef WRITEX
}

extern "C" void kernel_launch(void* const* d_in, const int* in_sizes, int n_in,
                              void* d_out, int out_size, void* d_ws, size_t ws_size,
                              hipStream_t stream) {
  const float* h = (const float*)d_in[0];
  const int* esrc = (const int*)d_in[1];
  const int* edst = (const int*)d_in[2];
  const float* Ws1 = (const float*)d_in[3];
  const float* Wn1 = (const float*)d_in[4];
  const float* b1 = (const float*)d_in[5];
  const float* Ws2 = (const float*)d_in[6];
  const float* Wn2 = (const float*)d_in[7];
  const float* b2 = (const float*)d_in[8];
  float* out = (float*)d_out;

  const int N = in_sizes[0] / 128;  // 100000
  const int E = in_sizes[1];        // 1600000
  const int P = (N + 255) >> 8;     // 391 buckets (<=512)

  char* base = (char*)d_ws;
  size_t off = 0;
  auto alloc = [&](size_t bytes) {
    size_t o = off;
    off += (bytes + 255) & ~(size_t)255;
    return o;
  };
  int* deg = (int*)(base + alloc((size_t)N * 4));
  int* rs = (int*)(base + alloc((size_t)N * 4));
  int* bcnt = (int*)(base + alloc(513 * 4));
  int* bbase = (int*)(base + alloc(513 * 4));
  int* bcur = (int*)(base + alloc(513 * 4));
  uint* bed = (uint*)(base + alloc((size_t)E * 4));
  int* col = (int*)(base + alloc((size_t)E * 4));
  ushort* hb = (ushort*)(base + alloc((size_t)N * 128 * 2));
  uchar* h8 = (uchar*)(base + alloc((size_t)N * 128));
  ushort* aggb = (ushort*)(base + alloc((size_t)N * 128 * 2));
  ushort* Wt1 = (ushort*)(base + alloc(128 * 256 * 2));
  ushort* Wt2cat = (ushort*)(base + alloc(128 * 128 * 2));
  // overlays:
  uchar* p8 = (uchar*)bed;   // [N][64] fp8: bed dead after k_bcsr; N*64 <= E*4
  float* s2f = (float*)aggb; // [N][64] f32: row ranges owned by the writing tile

  const int NCH = (E + 8191) / 8192;
  const int NT = (N + 63) / 64;       // 1563 M-tiles
  const int n8 = N * 128 / 8;
  const int CB = (n8 + 255) / 256;    // cast blocks
  const int WB = (128 * 256 + 128 * 128) / 256;  // 192 weight blocks

  (void)hipMemsetAsync(bcnt, 0, 513 * 4, stream);
  k_bhist<<<NCH, 256, 0, stream>>>(edst, bcnt, E);
  k_bscan<<<1, 512, 0, stream>>>(bcnt, bbase, bcur, P, E);
  k_bscatter<<<NCH, 256, 0, stream>>>(edst, esrc, bcur, bed, E, P);
  k_bcsr<<<P, 256, 0, stream>>>(bed, bbase, deg, rs, col, N);

  k_prep<<<CB + WB, 256, 0, stream>>>(h, Ws1, Wn1, Ws2, Wn2, hb, h8, Wt1,
                                      Wt2cat, n8, CB);

  // Layer 1 aggregate, then persistent fused GEMM1+GEMM2 -> p2 (fp8) + s2 (f32)
  k_agg1<<<(N + 31) / 32, 256, 0, stream>>>(h8, col, rs, deg, aggb, N);
  k_persist<<<256, 512, 0, stream>>>(hb, aggb, Wt1, Wt2cat, b1, b2, p8, s2f, N, NT);
  // Layer 2 fused gather + add + relu
  k_agg_out<<<(N + 63) / 64, 256, 0, stream>>>(p8, s2f, col, rs, deg, out, N);
}